// Round 17
// baseline (790.201 us; speedup 1.0000x reference)
//
#include <hip/hip_runtime.h>
#include <cstdint>
#include <cstddef>

typedef unsigned short u16;
typedef short bf16x8 __attribute__((ext_vector_type(8)));
typedef float f32x4 __attribute__((ext_vector_type(4)));

#define LN_EPS 1e-6f

// async global->LDS, 16B per lane; LDS dest is wave-uniform base + lane*16
#define GLD16(gsrc, ldst) \
    __builtin_amdgcn_global_load_lds( \
        (const __attribute__((address_space(1))) void*)(gsrc), \
        (__attribute__((address_space(3))) void*)(ldst), 16, 0, 0)

__device__ inline u16 f2bf(float f) {
    uint32_t x = __float_as_uint(f);
    uint32_t r = (x + 0x7fffu + ((x >> 16) & 1u)) >> 16;   // RNE
    return (u16)r;
}
__device__ inline float bf2f(u16 u) { return __uint_as_float(((uint32_t)u) << 16); }

// ---------------- block reductions (256 threads = 4 waves) ----------------
__device__ inline float blk_sum(float v, float* s) {
    #pragma unroll
    for (int o = 32; o > 0; o >>= 1) v += __shfl_xor(v, o);
    __syncthreads();
    if ((threadIdx.x & 63) == 0) s[threadIdx.x >> 6] = v;
    __syncthreads();
    return s[0] + s[1] + s[2] + s[3];
}

// =====================================================================
// 8-phase 256xBN GEMM (m201-template port; validated R3/R5-R16).
// C[m][n] = sum_k A[m][k]*B[n][k], row-major k-contiguous.
// R17 change: DEEP PREFETCH — all 4 next-tile half-tiles issued in
// phases 1-2 (kh0 pair @P1, kh1 pair @P2), so the mid-tile checkpoint's
// wait target has ~4 phases (~640cy) of cover instead of 2 (~320cy),
// matching HBM latency (~900cy). Checkpoint counts (oldest-first vmcnt
// semantics): mid = in-flight next-tile loads (8 for BN=256, 6 for
// BN=128); end = next-tile kh1 pair (4 / 3).
// MT: M-tiles per block. Grid (N/BN, M/(256*MT), Z). Z split-K: A,B
// advance z*K elems (K = per-slice depth), C advances z*zCstride.
// MODE: 0 f32*scale | 1 f32 relu(acc+bias) | 2 f32 += relu(acc+bias)
//       | 3 bf16*scale | 5 bf16(exp(acc*scale))  [softmax E-values]
// NOTE (R15): no NT stores — partial-line u16 NT stores amplify writes.
// =====================================================================
template<int BN, int MODE, int MT>
__global__ __launch_bounds__(512, 2) void gemm8_k(
    const u16* __restrict__ A, int lda, const u16* __restrict__ B, int ldb,
    float* __restrict__ Cf, u16* __restrict__ Cb,
    const float* __restrict__ bias, int ldc, int K, size_t zCstride, float scale)
{
    constexpr int NFRAG = BN / 64;          // n-fragments per wave
    constexpr int BKH   = BN * 32;          // B per-kh elems
    constexpr int BUFE  = 16384 + BN * 64;  // elems per buffer (A 2kh + B 2kh)
    __shared__ u16 lds[2 * BUFE];

    const int tid  = threadIdx.x;
    const int lane = tid & 63, wid = tid >> 6;
    const int wr = wid >> 2, wc = wid & 3;
    const int fr = lane & 15, fg = lane >> 4;

    const int gx  = gridDim.x, nwg = gx * gridDim.y;
    const int bid = blockIdx.y * gx + blockIdx.x;
    const int wg  = (bid & 7) * (nwg >> 3) + (bid >> 3);   // XCD-contiguous
    const int n0  = (wg % gx) * BN;
    const int m0b = (wg / gx) * (256 * MT);

    const u16* Az = A + (size_t)blockIdx.z * K;
    const u16* Bz = B + (size_t)blockIdx.z * K;
    float* Cfz = Cf ? Cf + (size_t)blockIdx.z * zCstride : nullptr;

    // staging geometry: thread covers row sr (and sr+128 for 256-row tiles)
    const int sr = tid >> 2;
    const int kb = ((tid & 3) ^ ((sr >> 1) & 3)) * 8;   // pre-swizzled col

    const int NT = K >> 6;

    // mid ckpt: leave all next-tile loads (issued P1/P2) in flight,
    // wait only for current tile's kh1 pair (issued 4 phases earlier).
    #define CKPT_MID() do { if constexpr (BN == 256) asm volatile("s_waitcnt vmcnt(8)" ::: "memory"); \
                            else                     asm volatile("s_waitcnt vmcnt(6)" ::: "memory"); } while (0)
    // end ckpt: wait for next tile's kh0 pair (oldest in queue), leave kh1 pair.
    #define CKPT_END() do { if constexpr (BN == 256) asm volatile("s_waitcnt vmcnt(4)" ::: "memory"); \
                            else                     asm volatile("s_waitcnt vmcnt(3)" ::: "memory"); } while (0)

    // per-lane read bases (u16 units)
    const int swz   = (fg ^ ((fr >> 1) & 3)) * 8;
    const int baseA = (wr * 128 + fr) * 32 + swz;
    const int baseB = 16384 + (wc * (BN / 4) + fr) * 32 + swz;

    for (int mt = 0; mt < MT; ++mt) {
        const int m0 = m0b + mt * 256;

        auto STAGE = [&](int buf, int isB, int kh, int kt) {
            const u16* s0 = isB ? Bz : Az;
            const int  ld = isB ? ldb : lda;
            const int  rb = isB ? n0 : m0;
            const int  k0 = kt * 64 + kh * 32 + kb;
            u16* dst = &lds[buf * BUFE + (isB ? 16384 : 0) + kh * (isB ? BKH : 8192) + tid * 8];
            GLD16(s0 + (size_t)(rb + sr) * ld + k0, dst);
            if (!isB || BN == 256)
                GLD16(s0 + (size_t)(rb + 128 + sr) * ld + k0, dst + 4096);
        };

        f32x4 acc[8][NFRAG];
        {
            f32x4 z = {0.f, 0.f, 0.f, 0.f};
            #pragma unroll
            for (int m = 0; m < 8; m++)
                #pragma unroll
                for (int n = 0; n < NFRAG; n++) acc[m][n] = z;
        }

        // prologue: A-kh0, B-kh0, A-kh1, B-kh1 of tile 0
        STAGE(0, 0, 0, 0); STAGE(0, 1, 0, 0); STAGE(0, 0, 1, 0); STAGE(0, 1, 1, 0);
        CKPT_END();                                        // kh0 pair landed
        __builtin_amdgcn_s_barrier();

        bf16x8 af[4], bv[NFRAG];

        for (int t = 0; t < NT; ++t) {
            const int  aO  = (t & 1) * BUFE;
            const int  nxt = (t & 1) ^ 1;
            const bool pre = (t + 1 < NT);

            // ---- phase 1: (ms=0, ks=0) -- issue next-tile kh0 pair
            #pragma unroll
            for (int m = 0; m < 4; m++) af[m] = *(const bf16x8*)&lds[baseA + aO + m * 512];
            #pragma unroll
            for (int n = 0; n < NFRAG; n++) bv[n] = *(const bf16x8*)&lds[baseB + aO + n * 512];
            if (pre) { STAGE(nxt, 0, 0, t + 1); STAGE(nxt, 1, 0, t + 1); }
            __builtin_amdgcn_s_barrier();
            asm volatile("s_waitcnt lgkmcnt(0)" ::: "memory");
            __builtin_amdgcn_sched_barrier(0);
            __builtin_amdgcn_s_setprio(1);
            #pragma unroll
            for (int m = 0; m < 4; m++)
                #pragma unroll
                for (int n = 0; n < NFRAG; n++)
                    acc[m][n] = __builtin_amdgcn_mfma_f32_16x16x32_bf16(af[m], bv[n], acc[m][n], 0, 0, 0);
            __builtin_amdgcn_s_setprio(0);
            __builtin_amdgcn_s_barrier();

            // ---- phase 2: (ms=1, ks=0) -- issue next-tile kh1 pair; ckpt kh1(t)
            #pragma unroll
            for (int m = 0; m < 4; m++) af[m] = *(const bf16x8*)&lds[baseA + aO + (4 + m) * 512];
            if (pre) { STAGE(nxt, 0, 1, t + 1); STAGE(nxt, 1, 1, t + 1); }
            __builtin_amdgcn_s_barrier();
            asm volatile("s_waitcnt lgkmcnt(0)" ::: "memory");
            __builtin_amdgcn_sched_barrier(0);
            __builtin_amdgcn_s_setprio(1);
            #pragma unroll
            for (int m = 0; m < 4; m++)
                #pragma unroll
                for (int n = 0; n < NFRAG; n++)
                    acc[4 + m][n] = __builtin_amdgcn_mfma_f32_16x16x32_bf16(af[m], bv[n], acc[4 + m][n], 0, 0, 0);
            __builtin_amdgcn_s_setprio(0);
            if (pre) { CKPT_MID(); }
            else     { asm volatile("s_waitcnt vmcnt(0)" ::: "memory"); }
            __builtin_amdgcn_sched_barrier(0);
            __builtin_amdgcn_s_barrier();

            // ---- phase 3: (ms=0, ks=1)
            #pragma unroll
            for (int m = 0; m < 4; m++) af[m] = *(const bf16x8*)&lds[baseA + aO + 8192 + m * 512];
            #pragma unroll
            for (int n = 0; n < NFRAG; n++) bv[n] = *(const bf16x8*)&lds[baseB + aO + BKH + n * 512];
            __builtin_amdgcn_s_barrier();
            asm volatile("s_waitcnt lgkmcnt(0)" ::: "memory");
            __builtin_amdgcn_sched_barrier(0);
            __builtin_amdgcn_s_setprio(1);
            #pragma unroll
            for (int m = 0; m < 4; m++)
                #pragma unroll
                for (int n = 0; n < NFRAG; n++)
                    acc[m][n] = __builtin_amdgcn_mfma_f32_16x16x32_bf16(af[m], bv[n], acc[m][n], 0, 0, 0);
            __builtin_amdgcn_s_setprio(0);
            __builtin_amdgcn_s_barrier();

            // ---- phase 4: (ms=1, ks=1); ckpt kh0(t+1)
            #pragma unroll
            for (int m = 0; m < 4; m++) af[m] = *(const bf16x8*)&lds[baseA + aO + 8192 + (4 + m) * 512];
            __builtin_amdgcn_s_barrier();
            asm volatile("s_waitcnt lgkmcnt(0)" ::: "memory");
            __builtin_amdgcn_sched_barrier(0);
            __builtin_amdgcn_s_setprio(1);
            #pragma unroll
            for (int m = 0; m < 4; m++)
                #pragma unroll
                for (int n = 0; n < NFRAG; n++)
                    acc[4 + m][n] = __builtin_amdgcn_mfma_f32_16x16x32_bf16(af[m], bv[n], acc[4 + m][n], 0, 0, 0);
            __builtin_amdgcn_s_setprio(0);
            if (pre) { CKPT_END(); }
            __builtin_amdgcn_sched_barrier(0);
            __builtin_amdgcn_s_barrier();
        }

        // epilogue: D layout col = lane&15, row = (lane>>4)*4 + reg [HW-verified]
        #pragma unroll
        for (int m = 0; m < 8; m++)
            #pragma unroll
            for (int n = 0; n < NFRAG; n++)
                #pragma unroll
                for (int r = 0; r < 4; r++) {
                    int row = m0 + wr * 128 + m * 16 + fg * 4 + r;
                    int col = n0 + wc * (BN / 4) + n * 16 + fr;
                    size_t idx = (size_t)row * ldc + col;
                    float v = acc[m][n][r] * scale;
                    if (MODE == 0) {
                        Cfz[idx] = v;
                    } else if (MODE == 1) {
                        Cfz[idx] = fmaxf(v + bias[col], 0.f);
                    } else if (MODE == 2) {
                        Cfz[idx] += fmaxf(v + bias[col], 0.f);
                    } else if (MODE == 3) {
                        Cb[idx] = f2bf(v);
                    } else {                       // MODE 5: unnormalized softmax E
                        Cb[idx] = f2bf(__expf(v));
                    }
                }
    }
    #undef CKPT_MID
    #undef CKPT_END
}

// ---------------- elementwise / converts ----------------
// six 1024x1024 weight converts in one dispatch (grid 3072).
// w==0 (Wq) is pre-scaled by 0.06 (folded from the Q projection).
__global__ __launch_bounds__(256) void cvt6_k(
    const float* __restrict__ s0, const float* __restrict__ s1, const float* __restrict__ s2,
    const float* __restrict__ s3, const float* __restrict__ s4, const float* __restrict__ s5,
    u16* __restrict__ d0, u16* __restrict__ d1, u16* __restrict__ d2,
    u16* __restrict__ d3, u16* __restrict__ d4, u16* __restrict__ d5) {
    int w = blockIdx.x >> 9;
    const float* s = (w == 0) ? s0 : (w == 1) ? s1 : (w == 2) ? s2 : (w == 3) ? s3 : (w == 4) ? s4 : s5;
    u16*         d = (w == 0) ? d0 : (w == 1) ? d1 : (w == 2) ? d2 : (w == 3) ? d3 : (w == 4) ? d4 : d5;
    float sc = (w == 0) ? 0.06f : 1.0f;
    int i = (blockIdx.x & 511) * 256 + threadIdx.x;
    const float4* sf = reinterpret_cast<const float4*>(s);
    float4 a = sf[2 * i], b = sf[2 * i + 1];
    union { u16 u[8]; int4 v; } t;
    t.u[0] = f2bf(a.x * sc); t.u[1] = f2bf(a.y * sc); t.u[2] = f2bf(a.z * sc); t.u[3] = f2bf(a.w * sc);
    t.u[4] = f2bf(b.x * sc); t.u[5] = f2bf(b.y * sc); t.u[6] = f2bf(b.z * sc); t.u[7] = f2bf(b.w * sc);
    reinterpret_cast<int4*>(d)[i] = t.v;
}

// yb = bf16(y0 + y1)  (split-K PV reduction fused into the convert)
__global__ __launch_bounds__(256) void cvt2_k(const float* __restrict__ s0, const float* __restrict__ s1,
                                              u16* __restrict__ d) {
    int i = blockIdx.x * 256 + threadIdx.x;
    const float4* f0 = reinterpret_cast<const float4*>(s0);
    const float4* f1 = reinterpret_cast<const float4*>(s1);
    float4 a = f0[2 * i], b = f0[2 * i + 1];
    float4 c = f1[2 * i], e = f1[2 * i + 1];
    union { u16 u[8]; int4 v; } t;
    t.u[0] = f2bf(a.x + c.x); t.u[1] = f2bf(a.y + c.y);
    t.u[2] = f2bf(a.z + c.z); t.u[3] = f2bf(a.w + c.w);
    t.u[4] = f2bf(b.x + e.x); t.u[5] = f2bf(b.y + e.y);
    t.u[6] = f2bf(b.z + e.z); t.u[7] = f2bf(b.w + e.w);
    reinterpret_cast<int4*>(d)[i] = t.v;
}

// fused: xb = bf16(x); d1/d2/d3 = bf16(|x[i+{1,2,4}] - x[i]|) (rows>=8188 zero)
__global__ __launch_bounds__(256) void diff3x_k(const float* __restrict__ x,
                                                u16* __restrict__ d1, u16* __restrict__ d2,
                                                u16* __restrict__ d3, u16* __restrict__ xb) {
    int i4 = blockIdx.x * 256 + threadIdx.x;    // float4 index; 256 per row
    int row = i4 >> 8;
    const float4* xf = reinterpret_cast<const float4*>(x);
    float4 b = xf[i4];
    ushort4 ox;
    ox.x = f2bf(b.x); ox.y = f2bf(b.y); ox.z = f2bf(b.z); ox.w = f2bf(b.w);
    reinterpret_cast<ushort4*>(xb)[i4] = ox;
    ushort4 o1, o2, o3;
    if (row < 8188) {
        float4 a1 = xf[i4 + (1 << 8)];
        float4 a2 = xf[i4 + (2 << 8)];
        float4 a3 = xf[i4 + (4 << 8)];
        o1.x = f2bf(fabsf(a1.x - b.x)); o1.y = f2bf(fabsf(a1.y - b.y));
        o1.z = f2bf(fabsf(a1.z - b.z)); o1.w = f2bf(fabsf(a1.w - b.w));
        o2.x = f2bf(fabsf(a2.x - b.x)); o2.y = f2bf(fabsf(a2.y - b.y));
        o2.z = f2bf(fabsf(a2.z - b.z)); o2.w = f2bf(fabsf(a2.w - b.w));
        o3.x = f2bf(fabsf(a3.x - b.x)); o3.y = f2bf(fabsf(a3.y - b.y));
        o3.z = f2bf(fabsf(a3.z - b.z)); o3.w = f2bf(fabsf(a3.w - b.w));
    } else {
        o1.x = o1.y = o1.z = o1.w = 0;
        o2 = o1; o3 = o1;
    }
    reinterpret_cast<ushort4*>(d1)[i4] = o1;
    reinterpret_cast<ushort4*>(d2)[i4] = o2;
    reinterpret_cast<ushort4*>(d3)[i4] = o3;
}

__global__ __launch_bounds__(256) void tail_k(const float* __restrict__ x, float* __restrict__ mn) {
    int i = blockIdx.x * 256 + threadIdx.x;
    mn[8188 * 1024 + i] = x[8188 * 1024 + i];
}

// ---------------- row-sum of bf16 E: rowl = 1/sum(E[r][:]) ----------------
__global__ __launch_bounds__(256) void stats_k(const u16* __restrict__ E,
                                               float* __restrict__ rowl) {
    __shared__ float red[4];
    int r = blockIdx.x, tid = threadIdx.x;
    const int4* src = reinterpret_cast<const int4*>(E + (size_t)r * 8192);
    float sum = 0.f;
    #pragma unroll
    for (int j = 0; j < 4; j++) {
        int4 v = src[tid + 256 * j];
        const u16* u = reinterpret_cast<const u16*>(&v);
        #pragma unroll
        for (int k = 0; k < 8; k++) sum += bf2f(u[k]);
    }
    sum = blk_sum(sum, red);
    if (tid == 0) rowl[r] = 1.0f / sum;
}

// ---------------- fused normalize + dual-write (aw f32 rows, ST bf16 transposed) ----
// E is 8192x8192 bf16 (unnormalized exp). Grid (128, 128).
__global__ __launch_bounds__(256) void nt_k(const u16* __restrict__ E,
                                            const float* __restrict__ rowl,
                                            float* __restrict__ aw,
                                            u16* __restrict__ ST) {
    __shared__ u16 t[64][72];
    int r0 = blockIdx.y * 64, c0 = blockIdx.x * 64;
    int tid = threadIdx.x;
    #pragma unroll
    for (int p = 0; p < 2; p++) {
        int q = p * 256 + tid;
        int r = q >> 3, c8 = q & 7;
        int4 v = *reinterpret_cast<const int4*>(E + (size_t)(r0 + r) * 8192 + c0 + c8 * 8);
        const u16* u = reinterpret_cast<const u16*>(&v);
        float li = rowl[r0 + r];
        float f[8];
        #pragma unroll
        for (int k = 0; k < 8; k++) {
            f[k] = bf2f(u[k]) * li;
            t[c8 * 8 + k][r] = f2bf(f[k]);
        }
        float4 w0, w1;
        w0.x = f[0]; w0.y = f[1]; w0.z = f[2]; w0.w = f[3];
        w1.x = f[4]; w1.y = f[5]; w1.z = f[6]; w1.w = f[7];
        float4* dst = reinterpret_cast<float4*>(aw + (size_t)(r0 + r) * 8192 + c0 + c8 * 8);
        dst[0] = w0; dst[1] = w1;
    }
    __syncthreads();
    #pragma unroll
    for (int p = 0; p < 2; p++) {
        int q = p * 256 + tid;
        int rr = q >> 3, cc = q & 7;
        *reinterpret_cast<int4*>(ST + (size_t)(c0 + rr) * 8192 + r0 + cc * 8) =
            *reinterpret_cast<const int4*>(&t[rr][cc * 8]);
    }
}

// bf16 transpose with leading dims; grid (srccols/64, srcrows/64)
__global__ __launch_bounds__(256) void transpose_bf16(const u16* __restrict__ src,
                                                      u16* __restrict__ dst,
                                                      int srcld, int dstld) {
    __shared__ u16 t[64][72];
    int r0 = blockIdx.y * 64, c0 = blockIdx.x * 64;
    int tid = threadIdx.x;
    #pragma unroll
    for (int p = 0; p < 2; p++) {
        int q = p * 256 + tid;
        int r = q >> 3, c8 = q & 7;
        int4 v = *(reinterpret_cast<const int4*>(src + (size_t)(r0 + r) * srcld + c0) + c8);
        const u16* u = reinterpret_cast<const u16*>(&v);
        #pragma unroll
        for (int k = 0; k < 8; k++) t[c8 * 8 + k][r] = u[k];
    }
    __syncthreads();
    #pragma unroll
    for (int p = 0; p < 2; p++) {
        int q = p * 256 + tid;
        int rr = q >> 3, cc = q & 7;
        *reinterpret_cast<int4*>(dst + (size_t)(c0 + rr) * dstld + r0 + cc * 8) =
            *reinterpret_cast<const int4*>(&t[rr][cc * 8]);
    }
}

// ---------------- LN kernels ----------------
__global__ __launch_bounds__(256) void ln_y_k(const float* __restrict__ y2, const float* __restrict__ mn,
                                              const float* __restrict__ g, const float* __restrict__ b,
                                              u16* __restrict__ zb) {
    __shared__ float red[4];
    int r = blockIdx.x, tid = threadIdx.x;
    float4 a = reinterpret_cast<const float4*>(y2 + (size_t)r * 1024)[tid];
    float4 c = reinterpret_cast<const float4*>(mn + (size_t)r * 1024)[tid];
    float4 v; v.x = a.x + c.x; v.y = a.y + c.y; v.z = a.z + c.z; v.w = a.w + c.w;
    float s  = v.x + v.y + v.z + v.w;
    float sq = v.x * v.x + v.y * v.y + v.z * v.z + v.w * v.w;
    s  = blk_sum(s, red);
    sq = blk_sum(sq, red);
    float mu = s * (1.0f / 1024.0f);
    float rs = rsqrtf(sq * (1.0f / 1024.0f) - mu * mu + LN_EPS);
    float4 gg = reinterpret_cast<const float4*>(g)[tid];
    float4 bb = reinterpret_cast<const float4*>(b)[tid];
    ushort4 o;
    o.x = f2bf((v.x - mu) * rs * gg.x + bb.x);
    o.y = f2bf((v.y - mu) * rs * gg.y + bb.y);
    o.z = f2bf((v.z - mu) * rs * gg.z + bb.z);
    o.w = f2bf((v.w - mu) * rs * gg.w + bb.w);
    reinterpret_cast<ushort4*>(zb + (size_t)r * 1024)[tid] = o;
}

__global__ __launch_bounds__(256) void ln_dot_k(const float* __restrict__ h, const float* __restrict__ g,
                                                const float* __restrict__ b, const float* __restrict__ kd,
                                                const float* __restrict__ kdb, float* __restrict__ out) {
    __shared__ float red[4];
    int r = blockIdx.x, tid = threadIdx.x;
    float4 v = reinterpret_cast<const float4*>(h + (size_t)r * 1024)[tid];
    float s  = v.x + v.y + v.z + v.w;
    float sq = v.x * v.x + v.y * v.y + v.z * v.z + v.w * v.w;
    s  = blk_sum(s, red);
    sq = blk_sum(sq, red);
    float mu = s * (1.0f / 1024.0f);
    float rs = rsqrtf(sq * (1.0f / 1024.0f) - mu * mu + LN_EPS);
    float4 gg = reinterpret_cast<const float4*>(g)[tid];
    float4 bb = reinterpret_cast<const float4*>(b)[tid];
    float4 kk = reinterpret_cast<const float4*>(kd)[tid];
    float part = ((v.x - mu) * rs * gg.x + bb.x) * kk.x
               + ((v.y - mu) * rs * gg.y + bb.y) * kk.y
               + ((v.z - mu) * rs * gg.z + bb.z) * kk.z
               + ((v.w - mu) * rs * gg.w + bb.w) * kk.w;
    part = blk_sum(part, red);
    if (tid == 0) out[r] = 1.0f / (1.0f + __expf(-(part + kdb[0])));
}

// ---------------- launch ----------------
extern "C" void kernel_launch(void* const* d_in, const int* in_sizes, int n_in,
                              void* d_out, int out_size, void* d_ws, size_t ws_size,
                              hipStream_t stream) {
    (void)in_sizes; (void)n_in; (void)out_size; (void)ws_size;
    const float* x    = (const float*)d_in[0];
    const float* Wq   = (const float*)d_in[2];
    const float* Wk   = (const float*)d_in[3];
    const float* Wv   = (const float*)d_in[4];
    const float* Wo   = (const float*)d_in[5];
    const float* fc1w = (const float*)d_in[6];
    const float* fc1b = (const float*)d_in[7];
    const float* kaw  = (const float*)d_in[8];
    const float* kab  = (const float*)d_in[9];
    const float* kdw  = (const float*)d_in[10];
    const float* kdb  = (const float*)d_in[11];
    const float* lyg  = (const float*)d_in[12];
    const float* lyb  = (const float*)d_in[13];
    const float* lkg  = (const float*)d_in[14];
    const float* lkb  = (const float*)d_in[15];

    float* out0 = (float*)d_out;
    float* aw   = out0 + 8192;

    char* base = (char*)d_ws;
    size_t off = 0;
    auto alloc = [&](size_t bytes) -> char* {
        char* p = base + off;
        off += (bytes + 255) & ~(size_t)255;
        return p;
    };
    const size_t NM = 8192ULL * 1024ULL;
    u16*   ST   = (u16*)alloc(8192ULL * 8192ULL * 2);   // 128MB aw^T bf16 (normalized)
    u16*   Eb   = (u16*)alloc(8192ULL * 8192ULL * 2);   // 128MB E=exp(S) bf16 (unnormalized)
    u16*   xb   = (u16*)alloc(NM * 2);
    u16*   QKVb = (u16*)alloc(8192ULL * 3072ULL * 2);   // 48MB: cols [Q*0.06 | K | V]
    u16*   Vt   = (u16*)alloc(NM * 2);
    u16*   d1   = (u16*)alloc(NM * 2);                  // later reused as zb
    u16*   d2   = (u16*)alloc(NM * 2);
    u16*   d3   = (u16*)alloc(NM * 2);
    u16*   yb   = (u16*)alloc(NM * 2);
    float* mn   = (float*)alloc(NM * 4);
    float* y01  = (float*)alloc(NM * 4 * 2);            // PV split-K slices
    float* y2   = (float*)alloc(NM * 4);
    float* hbuf = (float*)alloc(NM * 4);
    u16*   Wqkv = (u16*)alloc(3072ULL * 1024ULL * 2);   // rows [Wq|Wk|Wv]
    u16*   fwb  = (u16*)alloc(1048576ULL * 2);
    u16*   Wob  = (u16*)alloc(1048576ULL * 2);
    u16*   kwb  = (u16*)alloc(1048576ULL * 2);
    float* rowl = (float*)alloc(8192ULL * 4);
    u16*   zb   = d1;

    // 1) converts: x (+fused diffs) and weights (Wq pre-scaled 0.06)
    diff3x_k<<<8192, 256, 0, stream>>>(x, d1, d2, d3, xb);
    cvt6_k<<<3072, 256, 0, stream>>>(Wq, Wk, Wv, fc1w, Wo, kaw,
                                     Wqkv, Wqkv + 1048576, Wqkv + 2097152, fwb, Wob, kwb);

    // 2) mn branch: 3x BN=128 gemm8; tail rows
    gemm8_k<128, 1, 1><<<dim3(8, 32), 512, 0, stream>>>(
        d1, 1024, fwb, 1024, mn, nullptr, fc1b, 1024, 1024, 0, 1.0f);
    gemm8_k<128, 2, 1><<<dim3(8, 32), 512, 0, stream>>>(
        d2, 1024, fwb, 1024, mn, nullptr, fc1b, 1024, 1024, 0, 1.0f);
    gemm8_k<128, 2, 1><<<dim3(8, 32), 512, 0, stream>>>(
        d3, 1024, fwb, 1024, mn, nullptr, fc1b, 1024, 1024, 0, 1.0f);
    tail_k<<<16, 256, 0, stream>>>(x, mn);

    // 3) merged QKV projection: QKVb = xb @ [Wq*0.06;Wk;Wv]^T
    gemm8_k<128, 3, 1><<<dim3(24, 32), 512, 0, stream>>>(
        xb, 1024, Wqkv, 1024, nullptr, QKVb, nullptr, 3072, 1024, 0, 1.0f);
    transpose_bf16<<<dim3(16, 128), 256, 0, stream>>>(QKVb + 2048, Vt, 3072, 8192);

    // 4) logits in 4 chunks of 2048 rows (one full-chip round each)
    //    -> row sums -> fused normalize + dual-write (aw f32 + ST bf16^T)
    for (int c = 0; c < 4; ++c) {
        gemm8_k<256, 5, 1><<<dim3(32, 8), 512, 0, stream>>>(
            QKVb + (size_t)c * 2048 * 3072, 3072, QKVb + 1024, 3072,
            nullptr, Eb + (size_t)c * 2048 * 8192, nullptr, 8192, 1024, 0, 1.0f);
    }
    stats_k<<<8192, 256, 0, stream>>>(Eb, rowl);
    nt_k<<<dim3(128, 128), 256, 0, stream>>>(Eb, rowl, aw, ST);

    // 5) PV split-K z=2 (BN=256, K=4096 per slice): y01 slices; yb = bf16(y0+y1)
    gemm8_k<256, 0, 1><<<dim3(4, 32, 2), 512, 0, stream>>>(
        ST, 8192, Vt, 8192, y01, nullptr, nullptr, 1024, 4096, NM, 1.0f);
    cvt2_k<<<4096, 256, 0, stream>>>(y01, y01 + NM, yb);

    // 6) head: y2 = yb@Wo^T ; zb = LN(y2+mn) ; h = relu(zb@ka^T+b) ; out
    gemm8_k<128, 0, 1><<<dim3(8, 32), 512, 0, stream>>>(
        yb, 1024, Wob, 1024, y2, nullptr, nullptr, 1024, 1024, 0, 1.0f);
    ln_y_k<<<8192, 256, 0, stream>>>(y2, mn, lyg, lyb, zb);
    gemm8_k<128, 1, 1><<<dim3(8, 32), 512, 0, stream>>>(
        zb, 1024, kwb, 1024, hbuf, nullptr, kab, 1024, 1024, 0, 1.0f);
    ln_dot_k<<<8192, 256, 0, stream>>>(hbuf, lkg, lkb, kdw, kdb, out0);
}

// Round 18
// 717.288 us; speedup vs baseline: 1.1017x; 1.1017x over previous
//
#include <hip/hip_runtime.h>
#include <cstdint>
#include <cstddef>

typedef unsigned short u16;
typedef short bf16x8 __attribute__((ext_vector_type(8)));
typedef float f32x4 __attribute__((ext_vector_type(4)));

#define LN_EPS 1e-6f

// async global->LDS, 16B per lane; LDS dest is wave-uniform base + lane*16
#define GLD16(gsrc, ldst) \
    __builtin_amdgcn_global_load_lds( \
        (const __attribute__((address_space(1))) void*)(gsrc), \
        (__attribute__((address_space(3))) void*)(ldst), 16, 0, 0)

__device__ inline u16 f2bf(float f) {
    uint32_t x = __float_as_uint(f);
    uint32_t r = (x + 0x7fffu + ((x >> 16) & 1u)) >> 16;   // RNE
    return (u16)r;
}
__device__ inline float bf2f(u16 u) { return __uint_as_float(((uint32_t)u) << 16); }

// ---------------- block reductions (256 threads = 4 waves) ----------------
__device__ inline float blk_sum(float v, float* s) {
    #pragma unroll
    for (int o = 32; o > 0; o >>= 1) v += __shfl_xor(v, o);
    __syncthreads();
    if ((threadIdx.x & 63) == 0) s[threadIdx.x >> 6] = v;
    __syncthreads();
    return s[0] + s[1] + s[2] + s[3];
}

// =====================================================================
// 8-phase 256xBN GEMM (m201-template port; validated R3/R5-R13; R13 is
// the best-measured schedule — R15 NT stores, R16 chunked logits and
// R17 deep-prefetch all regressed or were neutral; keep this form).
// C[m][n] = sum_k A[m][k]*B[n][k], row-major k-contiguous.
// BN in {256,128}: 8 waves as 2(M)x4(N), per-wave 128 x BN/4.
// BK=64 staged as 2 k-halves; double-buffered LDS; counted vmcnt ckpts
// (4 for BN=256, 3 for BN=128) at phases 2/4 — never drain-0 mid-loop.
// LDS 16B-slot swizzle on global SOURCE col + ds_read addr (rule #21).
// MT: M-tiles per block (vertical loop). Grid (N/BN, M/(256*MT), Z).
// Z split-K: A,B advance z*K elems (K = per-slice depth), C advances
// z*zCstride floats. gridDim.x*gridDim.y % 8 == 0; 256 blocks/dispatch.
// MODE: 0 f32*scale | 1 f32 relu(acc+bias) | 2 f32 += relu(acc+bias)
//       | 3 bf16*scale | 5 bf16(exp(acc*scale))  [softmax E-values]
// =====================================================================
template<int BN, int MODE, int MT>
__global__ __launch_bounds__(512, 2) void gemm8_k(
    const u16* __restrict__ A, int lda, const u16* __restrict__ B, int ldb,
    float* __restrict__ Cf, u16* __restrict__ Cb,
    const float* __restrict__ bias, int ldc, int K, size_t zCstride, float scale)
{
    constexpr int NFRAG = BN / 64;          // n-fragments per wave
    constexpr int BKH   = BN * 32;          // B per-kh elems
    constexpr int BUFE  = 16384 + BN * 64;  // elems per buffer (A 2kh + B 2kh)
    __shared__ u16 lds[2 * BUFE];

    const int tid  = threadIdx.x;
    const int lane = tid & 63, wid = tid >> 6;
    const int wr = wid >> 2, wc = wid & 3;
    const int fr = lane & 15, fg = lane >> 4;

    const int gx  = gridDim.x, nwg = gx * gridDim.y;
    const int bid = blockIdx.y * gx + blockIdx.x;
    const int wg  = (bid & 7) * (nwg >> 3) + (bid >> 3);   // XCD-contiguous
    const int n0  = (wg % gx) * BN;
    const int m0b = (wg / gx) * (256 * MT);

    const u16* Az = A + (size_t)blockIdx.z * K;
    const u16* Bz = B + (size_t)blockIdx.z * K;
    float* Cfz = Cf ? Cf + (size_t)blockIdx.z * zCstride : nullptr;

    // staging geometry: thread covers row sr (and sr+128 for 256-row tiles)
    const int sr = tid >> 2;
    const int kb = ((tid & 3) ^ ((sr >> 1) & 3)) * 8;   // pre-swizzled col

    const int NT = K >> 6;

    #define CKPT_MID() do { if constexpr (BN == 256) asm volatile("s_waitcnt vmcnt(4)" ::: "memory"); \
                            else                     asm volatile("s_waitcnt vmcnt(3)" ::: "memory"); } while (0)

    // per-lane read bases (u16 units)
    const int swz   = (fg ^ ((fr >> 1) & 3)) * 8;
    const int baseA = (wr * 128 + fr) * 32 + swz;
    const int baseB = 16384 + (wc * (BN / 4) + fr) * 32 + swz;

    for (int mt = 0; mt < MT; ++mt) {
        const int m0 = m0b + mt * 256;

        auto STAGE = [&](int buf, int isB, int kh, int kt) {
            const u16* s0 = isB ? Bz : Az;
            const int  ld = isB ? ldb : lda;
            const int  rb = isB ? n0 : m0;
            const int  k0 = kt * 64 + kh * 32 + kb;
            u16* dst = &lds[buf * BUFE + (isB ? 16384 : 0) + kh * (isB ? BKH : 8192) + tid * 8];
            GLD16(s0 + (size_t)(rb + sr) * ld + k0, dst);
            if (!isB || BN == 256)
                GLD16(s0 + (size_t)(rb + 128 + sr) * ld + k0, dst + 4096);
        };

        f32x4 acc[8][NFRAG];
        {
            f32x4 z = {0.f, 0.f, 0.f, 0.f};
            #pragma unroll
            for (int m = 0; m < 8; m++)
                #pragma unroll
                for (int n = 0; n < NFRAG; n++) acc[m][n] = z;
        }

        // prologue: A-kh0, B-kh0, A-kh1, B-kh1 of tile 0
        STAGE(0, 0, 0, 0); STAGE(0, 1, 0, 0); STAGE(0, 0, 1, 0); STAGE(0, 1, 1, 0);
        CKPT_MID();                                        // kh0 group landed
        __builtin_amdgcn_s_barrier();

        bf16x8 af[4], bv[NFRAG];

        for (int t = 0; t < NT; ++t) {
            const int  aO  = (t & 1) * BUFE;
            const int  nxt = (t & 1) ^ 1;
            const bool pre = (t + 1 < NT);

            // ---- phase 1: (ms=0, ks=0)
            #pragma unroll
            for (int m = 0; m < 4; m++) af[m] = *(const bf16x8*)&lds[baseA + aO + m * 512];
            #pragma unroll
            for (int n = 0; n < NFRAG; n++) bv[n] = *(const bf16x8*)&lds[baseB + aO + n * 512];
            if (pre) STAGE(nxt, 0, 0, t + 1);
            __builtin_amdgcn_s_barrier();
            asm volatile("s_waitcnt lgkmcnt(0)" ::: "memory");
            __builtin_amdgcn_sched_barrier(0);
            __builtin_amdgcn_s_setprio(1);
            #pragma unroll
            for (int m = 0; m < 4; m++)
                #pragma unroll
                for (int n = 0; n < NFRAG; n++)
                    acc[m][n] = __builtin_amdgcn_mfma_f32_16x16x32_bf16(af[m], bv[n], acc[m][n], 0, 0, 0);
            __builtin_amdgcn_s_setprio(0);
            __builtin_amdgcn_s_barrier();

            // ---- phase 2: (ms=1, ks=0); ckpt kh1(t)
            #pragma unroll
            for (int m = 0; m < 4; m++) af[m] = *(const bf16x8*)&lds[baseA + aO + (4 + m) * 512];
            if (pre) STAGE(nxt, 1, 0, t + 1);
            __builtin_amdgcn_s_barrier();
            asm volatile("s_waitcnt lgkmcnt(0)" ::: "memory");
            __builtin_amdgcn_sched_barrier(0);
            __builtin_amdgcn_s_setprio(1);
            #pragma unroll
            for (int m = 0; m < 4; m++)
                #pragma unroll
                for (int n = 0; n < NFRAG; n++)
                    acc[4 + m][n] = __builtin_amdgcn_mfma_f32_16x16x32_bf16(af[m], bv[n], acc[4 + m][n], 0, 0, 0);
            __builtin_amdgcn_s_setprio(0);
            if (pre) { CKPT_MID(); }
            else     { asm volatile("s_waitcnt vmcnt(0)" ::: "memory"); }
            __builtin_amdgcn_sched_barrier(0);
            __builtin_amdgcn_s_barrier();

            // ---- phase 3: (ms=0, ks=1)
            #pragma unroll
            for (int m = 0; m < 4; m++) af[m] = *(const bf16x8*)&lds[baseA + aO + 8192 + m * 512];
            #pragma unroll
            for (int n = 0; n < NFRAG; n++) bv[n] = *(const bf16x8*)&lds[baseB + aO + BKH + n * 512];
            if (pre) STAGE(nxt, 0, 1, t + 1);
            __builtin_amdgcn_s_barrier();
            asm volatile("s_waitcnt lgkmcnt(0)" ::: "memory");
            __builtin_amdgcn_sched_barrier(0);
            __builtin_amdgcn_s_setprio(1);
            #pragma unroll
            for (int m = 0; m < 4; m++)
                #pragma unroll
                for (int n = 0; n < NFRAG; n++)
                    acc[m][n] = __builtin_amdgcn_mfma_f32_16x16x32_bf16(af[m], bv[n], acc[m][n], 0, 0, 0);
            __builtin_amdgcn_s_setprio(0);
            __builtin_amdgcn_s_barrier();

            // ---- phase 4: (ms=1, ks=1); ckpt kh0(t+1)
            #pragma unroll
            for (int m = 0; m < 4; m++) af[m] = *(const bf16x8*)&lds[baseA + aO + 8192 + (4 + m) * 512];
            if (pre) STAGE(nxt, 1, 1, t + 1);
            __builtin_amdgcn_s_barrier();
            asm volatile("s_waitcnt lgkmcnt(0)" ::: "memory");
            __builtin_amdgcn_sched_barrier(0);
            __builtin_amdgcn_s_setprio(1);
            #pragma unroll
            for (int m = 0; m < 4; m++)
                #pragma unroll
                for (int n = 0; n < NFRAG; n++)
                    acc[4 + m][n] = __builtin_amdgcn_mfma_f32_16x16x32_bf16(af[m], bv[n], acc[4 + m][n], 0, 0, 0);
            __builtin_amdgcn_s_setprio(0);
            if (pre) { CKPT_MID(); }
            __builtin_amdgcn_sched_barrier(0);
            __builtin_amdgcn_s_barrier();
        }

        // epilogue: D layout col = lane&15, row = (lane>>4)*4 + reg [HW-verified]
        #pragma unroll
        for (int m = 0; m < 8; m++)
            #pragma unroll
            for (int n = 0; n < NFRAG; n++)
                #pragma unroll
                for (int r = 0; r < 4; r++) {
                    int row = m0 + wr * 128 + m * 16 + fg * 4 + r;
                    int col = n0 + wc * (BN / 4) + n * 16 + fr;
                    size_t idx = (size_t)row * ldc + col;
                    float v = acc[m][n][r] * scale;
                    if (MODE == 0) {
                        Cfz[idx] = v;
                    } else if (MODE == 1) {
                        Cfz[idx] = fmaxf(v + bias[col], 0.f);
                    } else if (MODE == 2) {
                        Cfz[idx] += fmaxf(v + bias[col], 0.f);
                    } else if (MODE == 3) {
                        Cb[idx] = f2bf(v);
                    } else {                       // MODE 5: unnormalized softmax E
                        Cb[idx] = f2bf(__expf(v));
                    }
                }
    }
    #undef CKPT_MID
}

// ---------------- elementwise / converts ----------------
// six 1024x1024 weight converts in one dispatch (grid 3072).
// w==0 (Wq) is pre-scaled by 0.06 (folded from the Q projection).
__global__ __launch_bounds__(256) void cvt6_k(
    const float* __restrict__ s0, const float* __restrict__ s1, const float* __restrict__ s2,
    const float* __restrict__ s3, const float* __restrict__ s4, const float* __restrict__ s5,
    u16* __restrict__ d0, u16* __restrict__ d1, u16* __restrict__ d2,
    u16* __restrict__ d3, u16* __restrict__ d4, u16* __restrict__ d5) {
    int w = blockIdx.x >> 9;
    const float* s = (w == 0) ? s0 : (w == 1) ? s1 : (w == 2) ? s2 : (w == 3) ? s3 : (w == 4) ? s4 : s5;
    u16*         d = (w == 0) ? d0 : (w == 1) ? d1 : (w == 2) ? d2 : (w == 3) ? d3 : (w == 4) ? d4 : d5;
    float sc = (w == 0) ? 0.06f : 1.0f;
    int i = (blockIdx.x & 511) * 256 + threadIdx.x;
    const float4* sf = reinterpret_cast<const float4*>(s);
    float4 a = sf[2 * i], b = sf[2 * i + 1];
    union { u16 u[8]; int4 v; } t;
    t.u[0] = f2bf(a.x * sc); t.u[1] = f2bf(a.y * sc); t.u[2] = f2bf(a.z * sc); t.u[3] = f2bf(a.w * sc);
    t.u[4] = f2bf(b.x * sc); t.u[5] = f2bf(b.y * sc); t.u[6] = f2bf(b.z * sc); t.u[7] = f2bf(b.w * sc);
    reinterpret_cast<int4*>(d)[i] = t.v;
}

// yb = bf16(y0 + y1)  (split-K PV reduction fused into the convert)
__global__ __launch_bounds__(256) void cvt2_k(const float* __restrict__ s0, const float* __restrict__ s1,
                                              u16* __restrict__ d) {
    int i = blockIdx.x * 256 + threadIdx.x;
    const float4* f0 = reinterpret_cast<const float4*>(s0);
    const float4* f1 = reinterpret_cast<const float4*>(s1);
    float4 a = f0[2 * i], b = f0[2 * i + 1];
    float4 c = f1[2 * i], e = f1[2 * i + 1];
    union { u16 u[8]; int4 v; } t;
    t.u[0] = f2bf(a.x + c.x); t.u[1] = f2bf(a.y + c.y);
    t.u[2] = f2bf(a.z + c.z); t.u[3] = f2bf(a.w + c.w);
    t.u[4] = f2bf(b.x + e.x); t.u[5] = f2bf(b.y + e.y);
    t.u[6] = f2bf(b.z + e.z); t.u[7] = f2bf(b.w + e.w);
    reinterpret_cast<int4*>(d)[i] = t.v;
}

// fused: xb = bf16(x); d1/d2/d3 = bf16(|x[i+{1,2,4}] - x[i]|) (rows>=8188 zero)
__global__ __launch_bounds__(256) void diff3x_k(const float* __restrict__ x,
                                                u16* __restrict__ d1, u16* __restrict__ d2,
                                                u16* __restrict__ d3, u16* __restrict__ xb) {
    int i4 = blockIdx.x * 256 + threadIdx.x;    // float4 index; 256 per row
    int row = i4 >> 8;
    const float4* xf = reinterpret_cast<const float4*>(x);
    float4 b = xf[i4];
    ushort4 ox;
    ox.x = f2bf(b.x); ox.y = f2bf(b.y); ox.z = f2bf(b.z); ox.w = f2bf(b.w);
    reinterpret_cast<ushort4*>(xb)[i4] = ox;
    ushort4 o1, o2, o3;
    if (row < 8188) {
        float4 a1 = xf[i4 + (1 << 8)];
        float4 a2 = xf[i4 + (2 << 8)];
        float4 a3 = xf[i4 + (4 << 8)];
        o1.x = f2bf(fabsf(a1.x - b.x)); o1.y = f2bf(fabsf(a1.y - b.y));
        o1.z = f2bf(fabsf(a1.z - b.z)); o1.w = f2bf(fabsf(a1.w - b.w));
        o2.x = f2bf(fabsf(a2.x - b.x)); o2.y = f2bf(fabsf(a2.y - b.y));
        o2.z = f2bf(fabsf(a2.z - b.z)); o2.w = f2bf(fabsf(a2.w - b.w));
        o3.x = f2bf(fabsf(a3.x - b.x)); o3.y = f2bf(fabsf(a3.y - b.y));
        o3.z = f2bf(fabsf(a3.z - b.z)); o3.w = f2bf(fabsf(a3.w - b.w));
    } else {
        o1.x = o1.y = o1.z = o1.w = 0;
        o2 = o1; o3 = o1;
    }
    reinterpret_cast<ushort4*>(d1)[i4] = o1;
    reinterpret_cast<ushort4*>(d2)[i4] = o2;
    reinterpret_cast<ushort4*>(d3)[i4] = o3;
}

__global__ __launch_bounds__(256) void tail_k(const float* __restrict__ x, float* __restrict__ mn) {
    int i = blockIdx.x * 256 + threadIdx.x;
    mn[8188 * 1024 + i] = x[8188 * 1024 + i];
}

// ---------------- row-sum of bf16 E: rowl = 1/sum(E[r][:]) ----------------
__global__ __launch_bounds__(256) void stats_k(const u16* __restrict__ E,
                                               float* __restrict__ rowl) {
    __shared__ float red[4];
    int r = blockIdx.x, tid = threadIdx.x;
    const int4* src = reinterpret_cast<const int4*>(E + (size_t)r * 8192);
    float sum = 0.f;
    #pragma unroll
    for (int j = 0; j < 4; j++) {
        int4 v = src[tid + 256 * j];
        const u16* u = reinterpret_cast<const u16*>(&v);
        #pragma unroll
        for (int k = 0; k < 8; k++) sum += bf2f(u[k]);
    }
    sum = blk_sum(sum, red);
    if (tid == 0) rowl[r] = 1.0f / sum;
}

// ---------------- fused normalize + dual-write (aw f32 rows, ST bf16 transposed) ----
// E is 8192x8192 bf16 (unnormalized exp). Grid (128, 128).
__global__ __launch_bounds__(256) void nt_k(const u16* __restrict__ E,
                                            const float* __restrict__ rowl,
                                            float* __restrict__ aw,
                                            u16* __restrict__ ST) {
    __shared__ u16 t[64][72];
    int r0 = blockIdx.y * 64, c0 = blockIdx.x * 64;
    int tid = threadIdx.x;
    #pragma unroll
    for (int p = 0; p < 2; p++) {
        int q = p * 256 + tid;
        int r = q >> 3, c8 = q & 7;
        int4 v = *reinterpret_cast<const int4*>(E + (size_t)(r0 + r) * 8192 + c0 + c8 * 8);
        const u16* u = reinterpret_cast<const u16*>(&v);
        float li = rowl[r0 + r];
        float f[8];
        #pragma unroll
        for (int k = 0; k < 8; k++) {
            f[k] = bf2f(u[k]) * li;
            t[c8 * 8 + k][r] = f2bf(f[k]);
        }
        float4 w0, w1;
        w0.x = f[0]; w0.y = f[1]; w0.z = f[2]; w0.w = f[3];
        w1.x = f[4]; w1.y = f[5]; w1.z = f[6]; w1.w = f[7];
        float4* dst = reinterpret_cast<float4*>(aw + (size_t)(r0 + r) * 8192 + c0 + c8 * 8);
        dst[0] = w0; dst[1] = w1;
    }
    __syncthreads();
    #pragma unroll
    for (int p = 0; p < 2; p++) {
        int q = p * 256 + tid;
        int rr = q >> 3, cc = q & 7;
        *reinterpret_cast<int4*>(ST + (size_t)(c0 + rr) * 8192 + r0 + cc * 8) =
            *reinterpret_cast<const int4*>(&t[rr][cc * 8]);
    }
}

// bf16 transpose with leading dims; grid (srccols/64, srcrows/64)
__global__ __launch_bounds__(256) void transpose_bf16(const u16* __restrict__ src,
                                                      u16* __restrict__ dst,
                                                      int srcld, int dstld) {
    __shared__ u16 t[64][72];
    int r0 = blockIdx.y * 64, c0 = blockIdx.x * 64;
    int tid = threadIdx.x;
    #pragma unroll
    for (int p = 0; p < 2; p++) {
        int q = p * 256 + tid;
        int r = q >> 3, c8 = q & 7;
        int4 v = *(reinterpret_cast<const int4*>(src + (size_t)(r0 + r) * srcld + c0) + c8);
        const u16* u = reinterpret_cast<const u16*>(&v);
        #pragma unroll
        for (int k = 0; k < 8; k++) t[c8 * 8 + k][r] = u[k];
    }
    __syncthreads();
    #pragma unroll
    for (int p = 0; p < 2; p++) {
        int q = p * 256 + tid;
        int rr = q >> 3, cc = q & 7;
        *reinterpret_cast<int4*>(dst + (size_t)(c0 + rr) * dstld + r0 + cc * 8) =
            *reinterpret_cast<const int4*>(&t[rr][cc * 8]);
    }
}

// ---------------- LN kernels ----------------
__global__ __launch_bounds__(256) void ln_y_k(const float* __restrict__ y2, const float* __restrict__ mn,
                                              const float* __restrict__ g, const float* __restrict__ b,
                                              u16* __restrict__ zb) {
    __shared__ float red[4];
    int r = blockIdx.x, tid = threadIdx.x;
    float4 a = reinterpret_cast<const float4*>(y2 + (size_t)r * 1024)[tid];
    float4 c = reinterpret_cast<const float4*>(mn + (size_t)r * 1024)[tid];
    float4 v; v.x = a.x + c.x; v.y = a.y + c.y; v.z = a.z + c.z; v.w = a.w + c.w;
    float s  = v.x + v.y + v.z + v.w;
    float sq = v.x * v.x + v.y * v.y + v.z * v.z + v.w * v.w;
    s  = blk_sum(s, red);
    sq = blk_sum(sq, red);
    float mu = s * (1.0f / 1024.0f);
    float rs = rsqrtf(sq * (1.0f / 1024.0f) - mu * mu + LN_EPS);
    float4 gg = reinterpret_cast<const float4*>(g)[tid];
    float4 bb = reinterpret_cast<const float4*>(b)[tid];
    ushort4 o;
    o.x = f2bf((v.x - mu) * rs * gg.x + bb.x);
    o.y = f2bf((v.y - mu) * rs * gg.y + bb.y);
    o.z = f2bf((v.z - mu) * rs * gg.z + bb.z);
    o.w = f2bf((v.w - mu) * rs * gg.w + bb.w);
    reinterpret_cast<ushort4*>(zb + (size_t)r * 1024)[tid] = o;
}

__global__ __launch_bounds__(256) void ln_dot_k(const float* __restrict__ h, const float* __restrict__ g,
                                                const float* __restrict__ b, const float* __restrict__ kd,
                                                const float* __restrict__ kdb, float* __restrict__ out) {
    __shared__ float red[4];
    int r = blockIdx.x, tid = threadIdx.x;
    float4 v = reinterpret_cast<const float4*>(h + (size_t)r * 1024)[tid];
    float s  = v.x + v.y + v.z + v.w;
    float sq = v.x * v.x + v.y * v.y + v.z * v.z + v.w * v.w;
    s  = blk_sum(s, red);
    sq = blk_sum(sq, red);
    float mu = s * (1.0f / 1024.0f);
    float rs = rsqrtf(sq * (1.0f / 1024.0f) - mu * mu + LN_EPS);
    float4 gg = reinterpret_cast<const float4*>(g)[tid];
    float4 bb = reinterpret_cast<const float4*>(b)[tid];
    float4 kk = reinterpret_cast<const float4*>(kd)[tid];
    float part = ((v.x - mu) * rs * gg.x + bb.x) * kk.x
               + ((v.y - mu) * rs * gg.y + bb.y) * kk.y
               + ((v.z - mu) * rs * gg.z + bb.z) * kk.z
               + ((v.w - mu) * rs * gg.w + bb.w) * kk.w;
    part = blk_sum(part, red);
    if (tid == 0) out[r] = 1.0f / (1.0f + __expf(-(part + kdb[0])));
}

// ---------------- launch ----------------
extern "C" void kernel_launch(void* const* d_in, const int* in_sizes, int n_in,
                              void* d_out, int out_size, void* d_ws, size_t ws_size,
                              hipStream_t stream) {
    (void)in_sizes; (void)n_in; (void)out_size; (void)ws_size;
    const float* x    = (const float*)d_in[0];
    const float* Wq   = (const float*)d_in[2];
    const float* Wk   = (const float*)d_in[3];
    const float* Wv   = (const float*)d_in[4];
    const float* Wo   = (const float*)d_in[5];
    const float* fc1w = (const float*)d_in[6];
    const float* fc1b = (const float*)d_in[7];
    const float* kaw  = (const float*)d_in[8];
    const float* kab  = (const float*)d_in[9];
    const float* kdw  = (const float*)d_in[10];
    const float* kdb  = (const float*)d_in[11];
    const float* lyg  = (const float*)d_in[12];
    const float* lyb  = (const float*)d_in[13];
    const float* lkg  = (const float*)d_in[14];
    const float* lkb  = (const float*)d_in[15];

    float* out0 = (float*)d_out;
    float* aw   = out0 + 8192;

    char* base = (char*)d_ws;
    size_t off = 0;
    auto alloc = [&](size_t bytes) -> char* {
        char* p = base + off;
        off += (bytes + 255) & ~(size_t)255;
        return p;
    };
    const size_t NM = 8192ULL * 1024ULL;
    u16*   ST   = (u16*)alloc(8192ULL * 8192ULL * 2);   // 128MB aw^T bf16 (normalized)
    u16*   Eb   = (u16*)alloc(8192ULL * 8192ULL * 2);   // 128MB E=exp(S) bf16 (unnormalized)
    u16*   xb   = (u16*)alloc(NM * 2);
    u16*   QKVb = (u16*)alloc(8192ULL * 3072ULL * 2);   // 48MB: cols [Q*0.06 | K | V]
    u16*   Vt   = (u16*)alloc(NM * 2);
    u16*   d1   = (u16*)alloc(NM * 2);                  // later reused as zb
    u16*   d2   = (u16*)alloc(NM * 2);
    u16*   d3   = (u16*)alloc(NM * 2);
    u16*   yb   = (u16*)alloc(NM * 2);
    float* mn   = (float*)alloc(NM * 4);
    float* y01  = (float*)alloc(NM * 4 * 2);            // PV split-K slices
    float* y2   = (float*)alloc(NM * 4);
    float* hbuf = (float*)alloc(NM * 4);
    u16*   Wqkv = (u16*)alloc(3072ULL * 1024ULL * 2);   // rows [Wq|Wk|Wv]
    u16*   fwb  = (u16*)alloc(1048576ULL * 2);
    u16*   Wob  = (u16*)alloc(1048576ULL * 2);
    u16*   kwb  = (u16*)alloc(1048576ULL * 2);
    float* rowl = (float*)alloc(8192ULL * 4);
    u16*   zb   = d1;

    // 1) converts: x (+fused diffs) and weights (Wq pre-scaled 0.06)
    diff3x_k<<<8192, 256, 0, stream>>>(x, d1, d2, d3, xb);
    cvt6_k<<<3072, 256, 0, stream>>>(Wq, Wk, Wv, fc1w, Wo, kaw,
                                     Wqkv, Wqkv + 1048576, Wqkv + 2097152, fwb, Wob, kwb);

    // 2) mn branch: 3x BN=128 gemm8; tail rows
    gemm8_k<128, 1, 1><<<dim3(8, 32), 512, 0, stream>>>(
        d1, 1024, fwb, 1024, mn, nullptr, fc1b, 1024, 1024, 0, 1.0f);
    gemm8_k<128, 2, 1><<<dim3(8, 32), 512, 0, stream>>>(
        d2, 1024, fwb, 1024, mn, nullptr, fc1b, 1024, 1024, 0, 1.0f);
    gemm8_k<128, 2, 1><<<dim3(8, 32), 512, 0, stream>>>(
        d3, 1024, fwb, 1024, mn, nullptr, fc1b, 1024, 1024, 0, 1.0f);
    tail_k<<<16, 256, 0, stream>>>(x, mn);

    // 3) merged QKV projection: QKVb = xb @ [Wq*0.06;Wk;Wv]^T
    gemm8_k<128, 3, 1><<<dim3(24, 32), 512, 0, stream>>>(
        xb, 1024, Wqkv, 1024, nullptr, QKVb, nullptr, 3072, 1024, 0, 1.0f);
    transpose_bf16<<<dim3(16, 128), 256, 0, stream>>>(QKVb + 2048, Vt, 3072, 8192);

    // 4) single-pass softmax chain: E = exp(QK^T) bf16 (M-tiled logits, 1 round)
    //    -> row sums -> fused normalize + dual-write (aw f32 + ST bf16^T)
    gemm8_k<256, 5, 4><<<dim3(32, 8), 512, 0, stream>>>(
        QKVb, 3072, QKVb + 1024, 3072, nullptr, Eb, nullptr, 8192, 1024, 0, 1.0f);
    stats_k<<<8192, 256, 0, stream>>>(Eb, rowl);
    nt_k<<<dim3(128, 128), 256, 0, stream>>>(Eb, rowl, aw, ST);

    // 5) PV split-K z=2 (BN=256, K=4096 per slice): y01 slices; yb = bf16(y0+y1)
    gemm8_k<256, 0, 1><<<dim3(4, 32, 2), 512, 0, stream>>>(
        ST, 8192, Vt, 8192, y01, nullptr, nullptr, 1024, 4096, NM, 1.0f);
    cvt2_k<<<4096, 256, 0, stream>>>(y01, y01 + NM, yb);

    // 6) head: y2 = yb@Wo^T ; zb = LN(y2+mn) ; h = relu(zb@ka^T+b) ; out
    gemm8_k<128, 0, 1><<<dim3(8, 32), 512, 0, stream>>>(
        yb, 1024, Wob, 1024, y2, nullptr, nullptr, 1024, 1024, 0, 1.0f);
    ln_y_k<<<8192, 256, 0, stream>>>(y2, mn, lyg, lyb, zb);
    gemm8_k<128, 1, 1><<<dim3(8, 32), 512, 0, stream>>>(
        zb, 1024, kwb, 1024, hbuf, nullptr, kab, 1024, 1024, 0, 1.0f);
    ln_dot_k<<<8192, 256, 0, stream>>>(hbuf, lkg, lkb, kdw, kdb, out0);
}

// Round 19
// 714.587 us; speedup vs baseline: 1.1058x; 1.0038x over previous
//
#include <hip/hip_runtime.h>
#include <cstdint>
#include <cstddef>

typedef unsigned short u16;
typedef short bf16x8 __attribute__((ext_vector_type(8)));
typedef float f32x4 __attribute__((ext_vector_type(4)));

#define LN_EPS 1e-6f

// async global->LDS, 16B per lane; LDS dest is wave-uniform base + lane*16
#define GLD16(gsrc, ldst) \
    __builtin_amdgcn_global_load_lds( \
        (const __attribute__((address_space(1))) void*)(gsrc), \
        (__attribute__((address_space(3))) void*)(ldst), 16, 0, 0)

__device__ inline u16 f2bf(float f) {
    uint32_t x = __float_as_uint(f);
    uint32_t r = (x + 0x7fffu + ((x >> 16) & 1u)) >> 16;   // RNE
    return (u16)r;
}
__device__ inline float bf2f(u16 u) { return __uint_as_float(((uint32_t)u) << 16); }

// ---------------- block reductions (256 threads = 4 waves) ----------------
__device__ inline float blk_sum(float v, float* s) {
    #pragma unroll
    for (int o = 32; o > 0; o >>= 1) v += __shfl_xor(v, o);
    __syncthreads();
    if ((threadIdx.x & 63) == 0) s[threadIdx.x >> 6] = v;
    __syncthreads();
    return s[0] + s[1] + s[2] + s[3];
}

// =====================================================================
// 8-phase 256xBN GEMM (m201-template port; validated R3/R5-R13/R18; the
// R13 schedule is best-measured — R15 NT stores, R16 chunked logits and
// R17 deep-prefetch all regressed/neutral; keep this form).
// C[m][n] = sum_k A[m][k]*B[n][k], row-major k-contiguous.
// BN in {256,128}: 8 waves as 2(M)x4(N), per-wave 128 x BN/4.
// BK=64 staged as 2 k-halves; double-buffered LDS; counted vmcnt ckpts
// (4 for BN=256, 3 for BN=128) at phases 2/4 — never drain-0 mid-loop.
// LDS 16B-slot swizzle on global SOURCE col + ds_read addr (rule #21).
// MT: M-tiles per block (vertical loop). Grid (N/BN, M/(256*MT), Z).
// Z split-K: A,B advance z*K elems (K = per-slice depth), C advances
// z*zCstride floats. gridDim.x*gridDim.y % 8 == 0; 256 blocks/dispatch.
// MODE: 0 f32*scale | 1 f32 relu(acc+bias) | 2 f32 += relu(acc+bias)
//       | 3 bf16*scale | 5 bf16(exp(acc*scale)) to Cb + per-block
//         partial row-sums of bf16-rounded E into Cf[row*128 +
//         (wg%gx)*4 + wc]  (REQUIRES gx==32, BN==256; no atomics)
// =====================================================================
template<int BN, int MODE, int MT>
__global__ __launch_bounds__(512, 2) void gemm8_k(
    const u16* __restrict__ A, int lda, const u16* __restrict__ B, int ldb,
    float* __restrict__ Cf, u16* __restrict__ Cb,
    const float* __restrict__ bias, int ldc, int K, size_t zCstride, float scale)
{
    constexpr int NFRAG = BN / 64;          // n-fragments per wave
    constexpr int BKH   = BN * 32;          // B per-kh elems
    constexpr int BUFE  = 16384 + BN * 64;  // elems per buffer (A 2kh + B 2kh)
    __shared__ u16 lds[2 * BUFE];

    const int tid  = threadIdx.x;
    const int lane = tid & 63, wid = tid >> 6;
    const int wr = wid >> 2, wc = wid & 3;
    const int fr = lane & 15, fg = lane >> 4;

    const int gx  = gridDim.x, nwg = gx * gridDim.y;
    const int bid = blockIdx.y * gx + blockIdx.x;
    const int wg  = (bid & 7) * (nwg >> 3) + (bid >> 3);   // XCD-contiguous
    const int n0  = (wg % gx) * BN;
    const int m0b = (wg / gx) * (256 * MT);

    const u16* Az = A + (size_t)blockIdx.z * K;
    const u16* Bz = B + (size_t)blockIdx.z * K;
    float* Cfz = Cf ? Cf + (size_t)blockIdx.z * zCstride : nullptr;

    // staging geometry: thread covers row sr (and sr+128 for 256-row tiles)
    const int sr = tid >> 2;
    const int kb = ((tid & 3) ^ ((sr >> 1) & 3)) * 8;   // pre-swizzled col

    const int NT = K >> 6;

    #define CKPT_MID() do { if constexpr (BN == 256) asm volatile("s_waitcnt vmcnt(4)" ::: "memory"); \
                            else                     asm volatile("s_waitcnt vmcnt(3)" ::: "memory"); } while (0)

    // per-lane read bases (u16 units)
    const int swz   = (fg ^ ((fr >> 1) & 3)) * 8;
    const int baseA = (wr * 128 + fr) * 32 + swz;
    const int baseB = 16384 + (wc * (BN / 4) + fr) * 32 + swz;

    for (int mt = 0; mt < MT; ++mt) {
        const int m0 = m0b + mt * 256;

        auto STAGE = [&](int buf, int isB, int kh, int kt) {
            const u16* s0 = isB ? Bz : Az;
            const int  ld = isB ? ldb : lda;
            const int  rb = isB ? n0 : m0;
            const int  k0 = kt * 64 + kh * 32 + kb;
            u16* dst = &lds[buf * BUFE + (isB ? 16384 : 0) + kh * (isB ? BKH : 8192) + tid * 8];
            GLD16(s0 + (size_t)(rb + sr) * ld + k0, dst);
            if (!isB || BN == 256)
                GLD16(s0 + (size_t)(rb + 128 + sr) * ld + k0, dst + 4096);
        };

        f32x4 acc[8][NFRAG];
        {
            f32x4 z = {0.f, 0.f, 0.f, 0.f};
            #pragma unroll
            for (int m = 0; m < 8; m++)
                #pragma unroll
                for (int n = 0; n < NFRAG; n++) acc[m][n] = z;
        }

        // prologue: A-kh0, B-kh0, A-kh1, B-kh1 of tile 0
        STAGE(0, 0, 0, 0); STAGE(0, 1, 0, 0); STAGE(0, 0, 1, 0); STAGE(0, 1, 1, 0);
        CKPT_MID();                                        // kh0 group landed
        __builtin_amdgcn_s_barrier();

        bf16x8 af[4], bv[NFRAG];

        for (int t = 0; t < NT; ++t) {
            const int  aO  = (t & 1) * BUFE;
            const int  nxt = (t & 1) ^ 1;
            const bool pre = (t + 1 < NT);

            // ---- phase 1: (ms=0, ks=0)
            #pragma unroll
            for (int m = 0; m < 4; m++) af[m] = *(const bf16x8*)&lds[baseA + aO + m * 512];
            #pragma unroll
            for (int n = 0; n < NFRAG; n++) bv[n] = *(const bf16x8*)&lds[baseB + aO + n * 512];
            if (pre) STAGE(nxt, 0, 0, t + 1);
            __builtin_amdgcn_s_barrier();
            asm volatile("s_waitcnt lgkmcnt(0)" ::: "memory");
            __builtin_amdgcn_sched_barrier(0);
            __builtin_amdgcn_s_setprio(1);
            #pragma unroll
            for (int m = 0; m < 4; m++)
                #pragma unroll
                for (int n = 0; n < NFRAG; n++)
                    acc[m][n] = __builtin_amdgcn_mfma_f32_16x16x32_bf16(af[m], bv[n], acc[m][n], 0, 0, 0);
            __builtin_amdgcn_s_setprio(0);
            __builtin_amdgcn_s_barrier();

            // ---- phase 2: (ms=1, ks=0); ckpt kh1(t)
            #pragma unroll
            for (int m = 0; m < 4; m++) af[m] = *(const bf16x8*)&lds[baseA + aO + (4 + m) * 512];
            if (pre) STAGE(nxt, 1, 0, t + 1);
            __builtin_amdgcn_s_barrier();
            asm volatile("s_waitcnt lgkmcnt(0)" ::: "memory");
            __builtin_amdgcn_sched_barrier(0);
            __builtin_amdgcn_s_setprio(1);
            #pragma unroll
            for (int m = 0; m < 4; m++)
                #pragma unroll
                for (int n = 0; n < NFRAG; n++)
                    acc[4 + m][n] = __builtin_amdgcn_mfma_f32_16x16x32_bf16(af[m], bv[n], acc[4 + m][n], 0, 0, 0);
            __builtin_amdgcn_s_setprio(0);
            if (pre) { CKPT_MID(); }
            else     { asm volatile("s_waitcnt vmcnt(0)" ::: "memory"); }
            __builtin_amdgcn_sched_barrier(0);
            __builtin_amdgcn_s_barrier();

            // ---- phase 3: (ms=0, ks=1)
            #pragma unroll
            for (int m = 0; m < 4; m++) af[m] = *(const bf16x8*)&lds[baseA + aO + 8192 + m * 512];
            #pragma unroll
            for (int n = 0; n < NFRAG; n++) bv[n] = *(const bf16x8*)&lds[baseB + aO + BKH + n * 512];
            if (pre) STAGE(nxt, 0, 1, t + 1);
            __builtin_amdgcn_s_barrier();
            asm volatile("s_waitcnt lgkmcnt(0)" ::: "memory");
            __builtin_amdgcn_sched_barrier(0);
            __builtin_amdgcn_s_setprio(1);
            #pragma unroll
            for (int m = 0; m < 4; m++)
                #pragma unroll
                for (int n = 0; n < NFRAG; n++)
                    acc[m][n] = __builtin_amdgcn_mfma_f32_16x16x32_bf16(af[m], bv[n], acc[m][n], 0, 0, 0);
            __builtin_amdgcn_s_setprio(0);
            __builtin_amdgcn_s_barrier();

            // ---- phase 4: (ms=1, ks=1); ckpt kh0(t+1)
            #pragma unroll
            for (int m = 0; m < 4; m++) af[m] = *(const bf16x8*)&lds[baseA + aO + 8192 + (4 + m) * 512];
            if (pre) STAGE(nxt, 1, 1, t + 1);
            __builtin_amdgcn_s_barrier();
            asm volatile("s_waitcnt lgkmcnt(0)" ::: "memory");
            __builtin_amdgcn_sched_barrier(0);
            __builtin_amdgcn_s_setprio(1);
            #pragma unroll
            for (int m = 0; m < 4; m++)
                #pragma unroll
                for (int n = 0; n < NFRAG; n++)
                    acc[4 + m][n] = __builtin_amdgcn_mfma_f32_16x16x32_bf16(af[m], bv[n], acc[4 + m][n], 0, 0, 0);
            __builtin_amdgcn_s_setprio(0);
            if (pre) { CKPT_MID(); }
            __builtin_amdgcn_sched_barrier(0);
            __builtin_amdgcn_s_barrier();
        }

        // epilogue: D layout col = lane&15, row = (lane>>4)*4 + reg [HW-verified]
        if constexpr (MODE == 5) {
            // E store + per-block partial row sums (16-lane fr-group reduce,
            // one plain store per (row, nblk=wg%gx, wc); psum width 128)
            #pragma unroll
            for (int m = 0; m < 8; m++)
                #pragma unroll
                for (int r = 0; r < 4; r++) {
                    int row = m0 + wr * 128 + m * 16 + fg * 4 + r;
                    float rs = 0.f;
                    #pragma unroll
                    for (int n = 0; n < NFRAG; n++) {
                        int col = n0 + wc * (BN / 4) + n * 16 + fr;
                        u16 h = f2bf(__expf(acc[m][n][r] * scale));
                        Cb[(size_t)row * ldc + col] = h;
                        rs += bf2f(h);
                    }
                    rs += __shfl_xor(rs, 1); rs += __shfl_xor(rs, 2);
                    rs += __shfl_xor(rs, 4); rs += __shfl_xor(rs, 8);
                    if (fr == 0) Cf[(size_t)row * 128 + (wg % gx) * 4 + wc] = rs;
                }
        } else {
            #pragma unroll
            for (int m = 0; m < 8; m++)
                #pragma unroll
                for (int n = 0; n < NFRAG; n++)
                    #pragma unroll
                    for (int r = 0; r < 4; r++) {
                        int row = m0 + wr * 128 + m * 16 + fg * 4 + r;
                        int col = n0 + wc * (BN / 4) + n * 16 + fr;
                        size_t idx = (size_t)row * ldc + col;
                        float v = acc[m][n][r] * scale;
                        if (MODE == 0) {
                            Cfz[idx] = v;
                        } else if (MODE == 1) {
                            Cfz[idx] = fmaxf(v + bias[col], 0.f);
                        } else if (MODE == 2) {
                            Cfz[idx] += fmaxf(v + bias[col], 0.f);
                        } else {
                            Cb[idx] = f2bf(v);
                        }
                    }
        }
    }
    #undef CKPT_MID
}

// ---------------- elementwise / converts ----------------
// six 1024x1024 weight converts in one dispatch (grid 3072).
// w==0 (Wq) is pre-scaled by 0.06 (folded from the Q projection).
__global__ __launch_bounds__(256) void cvt6_k(
    const float* __restrict__ s0, const float* __restrict__ s1, const float* __restrict__ s2,
    const float* __restrict__ s3, const float* __restrict__ s4, const float* __restrict__ s5,
    u16* __restrict__ d0, u16* __restrict__ d1, u16* __restrict__ d2,
    u16* __restrict__ d3, u16* __restrict__ d4, u16* __restrict__ d5) {
    int w = blockIdx.x >> 9;
    const float* s = (w == 0) ? s0 : (w == 1) ? s1 : (w == 2) ? s2 : (w == 3) ? s3 : (w == 4) ? s4 : s5;
    u16*         d = (w == 0) ? d0 : (w == 1) ? d1 : (w == 2) ? d2 : (w == 3) ? d3 : (w == 4) ? d4 : d5;
    float sc = (w == 0) ? 0.06f : 1.0f;
    int i = (blockIdx.x & 511) * 256 + threadIdx.x;
    const float4* sf = reinterpret_cast<const float4*>(s);
    float4 a = sf[2 * i], b = sf[2 * i + 1];
    union { u16 u[8]; int4 v; } t;
    t.u[0] = f2bf(a.x * sc); t.u[1] = f2bf(a.y * sc); t.u[2] = f2bf(a.z * sc); t.u[3] = f2bf(a.w * sc);
    t.u[4] = f2bf(b.x * sc); t.u[5] = f2bf(b.y * sc); t.u[6] = f2bf(b.z * sc); t.u[7] = f2bf(b.w * sc);
    reinterpret_cast<int4*>(d)[i] = t.v;
}

// yb = bf16(y0 + y1)  (split-K PV reduction fused into the convert)
__global__ __launch_bounds__(256) void cvt2_k(const float* __restrict__ s0, const float* __restrict__ s1,
                                              u16* __restrict__ d) {
    int i = blockIdx.x * 256 + threadIdx.x;
    const float4* f0 = reinterpret_cast<const float4*>(s0);
    const float4* f1 = reinterpret_cast<const float4*>(s1);
    float4 a = f0[2 * i], b = f0[2 * i + 1];
    float4 c = f1[2 * i], e = f1[2 * i + 1];
    union { u16 u[8]; int4 v; } t;
    t.u[0] = f2bf(a.x + c.x); t.u[1] = f2bf(a.y + c.y);
    t.u[2] = f2bf(a.z + c.z); t.u[3] = f2bf(a.w + c.w);
    t.u[4] = f2bf(b.x + e.x); t.u[5] = f2bf(b.y + e.y);
    t.u[6] = f2bf(b.z + e.z); t.u[7] = f2bf(b.w + e.w);
    reinterpret_cast<int4*>(d)[i] = t.v;
}

// fused: xb = bf16(x); d1/d2/d3 = bf16(|x[i+{1,2,4}] - x[i]|) (rows>=8188 zero)
__global__ __launch_bounds__(256) void diff3x_k(const float* __restrict__ x,
                                                u16* __restrict__ d1, u16* __restrict__ d2,
                                                u16* __restrict__ d3, u16* __restrict__ xb) {
    int i4 = blockIdx.x * 256 + threadIdx.x;    // float4 index; 256 per row
    int row = i4 >> 8;
    const float4* xf = reinterpret_cast<const float4*>(x);
    float4 b = xf[i4];
    ushort4 ox;
    ox.x = f2bf(b.x); ox.y = f2bf(b.y); ox.z = f2bf(b.z); ox.w = f2bf(b.w);
    reinterpret_cast<ushort4*>(xb)[i4] = ox;
    ushort4 o1, o2, o3;
    if (row < 8188) {
        float4 a1 = xf[i4 + (1 << 8)];
        float4 a2 = xf[i4 + (2 << 8)];
        float4 a3 = xf[i4 + (4 << 8)];
        o1.x = f2bf(fabsf(a1.x - b.x)); o1.y = f2bf(fabsf(a1.y - b.y));
        o1.z = f2bf(fabsf(a1.z - b.z)); o1.w = f2bf(fabsf(a1.w - b.w));
        o2.x = f2bf(fabsf(a2.x - b.x)); o2.y = f2bf(fabsf(a2.y - b.y));
        o2.z = f2bf(fabsf(a2.z - b.z)); o2.w = f2bf(fabsf(a2.w - b.w));
        o3.x = f2bf(fabsf(a3.x - b.x)); o3.y = f2bf(fabsf(a3.y - b.y));
        o3.z = f2bf(fabsf(a3.z - b.z)); o3.w = f2bf(fabsf(a3.w - b.w));
    } else {
        o1.x = o1.y = o1.z = o1.w = 0;
        o2 = o1; o3 = o1;
    }
    reinterpret_cast<ushort4*>(d1)[i4] = o1;
    reinterpret_cast<ushort4*>(d2)[i4] = o2;
    reinterpret_cast<ushort4*>(d3)[i4] = o3;
}

__global__ __launch_bounds__(256) void tail_k(const float* __restrict__ x, float* __restrict__ mn) {
    int i = blockIdx.x * 256 + threadIdx.x;
    mn[8188 * 1024 + i] = x[8188 * 1024 + i];
}

// ---------------- reduce 128 partials/row -> rowl = 1/rowsum ----------------
__global__ __launch_bounds__(256) void reduce_k(const float* __restrict__ psum,
                                                float* __restrict__ rowl) {
    int r = blockIdx.x * 256 + threadIdx.x;     // 8192 rows
    const float4* p = reinterpret_cast<const float4*>(psum + (size_t)r * 128);
    float s = 0.f;
    #pragma unroll
    for (int j = 0; j < 32; j++) { float4 v = p[j]; s += v.x + v.y + v.z + v.w; }
    rowl[r] = 1.0f / s;
}

// ---------------- fused normalize + dual-write (aw f32 rows, ST bf16 transposed) ----
// E is 8192x8192 bf16 (unnormalized exp). Grid (128, 128).
__global__ __launch_bounds__(256) void nt_k(const u16* __restrict__ E,
                                            const float* __restrict__ rowl,
                                            float* __restrict__ aw,
                                            u16* __restrict__ ST) {
    __shared__ u16 t[64][72];
    int r0 = blockIdx.y * 64, c0 = blockIdx.x * 64;
    int tid = threadIdx.x;
    #pragma unroll
    for (int p = 0; p < 2; p++) {
        int q = p * 256 + tid;
        int r = q >> 3, c8 = q & 7;
        int4 v = *reinterpret_cast<const int4*>(E + (size_t)(r0 + r) * 8192 + c0 + c8 * 8);
        const u16* u = reinterpret_cast<const u16*>(&v);
        float li = rowl[r0 + r];
        float f[8];
        #pragma unroll
        for (int k = 0; k < 8; k++) {
            f[k] = bf2f(u[k]) * li;
            t[c8 * 8 + k][r] = f2bf(f[k]);
        }
        float4 w0, w1;
        w0.x = f[0]; w0.y = f[1]; w0.z = f[2]; w0.w = f[3];
        w1.x = f[4]; w1.y = f[5]; w1.z = f[6]; w1.w = f[7];
        float4* dst = reinterpret_cast<float4*>(aw + (size_t)(r0 + r) * 8192 + c0 + c8 * 8);
        dst[0] = w0; dst[1] = w1;
    }
    __syncthreads();
    #pragma unroll
    for (int p = 0; p < 2; p++) {
        int q = p * 256 + tid;
        int rr = q >> 3, cc = q & 7;
        *reinterpret_cast<int4*>(ST + (size_t)(c0 + rr) * 8192 + r0 + cc * 8) =
            *reinterpret_cast<const int4*>(&t[rr][cc * 8]);
    }
}

// bf16 transpose with leading dims; grid (srccols/64, srcrows/64)
__global__ __launch_bounds__(256) void transpose_bf16(const u16* __restrict__ src,
                                                      u16* __restrict__ dst,
                                                      int srcld, int dstld) {
    __shared__ u16 t[64][72];
    int r0 = blockIdx.y * 64, c0 = blockIdx.x * 64;
    int tid = threadIdx.x;
    #pragma unroll
    for (int p = 0; p < 2; p++) {
        int q = p * 256 + tid;
        int r = q >> 3, c8 = q & 7;
        int4 v = *(reinterpret_cast<const int4*>(src + (size_t)(r0 + r) * srcld + c0) + c8);
        const u16* u = reinterpret_cast<const u16*>(&v);
        #pragma unroll
        for (int k = 0; k < 8; k++) t[c8 * 8 + k][r] = u[k];
    }
    __syncthreads();
    #pragma unroll
    for (int p = 0; p < 2; p++) {
        int q = p * 256 + tid;
        int rr = q >> 3, cc = q & 7;
        *reinterpret_cast<int4*>(dst + (size_t)(c0 + rr) * dstld + r0 + cc * 8) =
            *reinterpret_cast<const int4*>(&t[rr][cc * 8]);
    }
}

// ---------------- LN kernels ----------------
__global__ __launch_bounds__(256) void ln_y_k(const float* __restrict__ y2, const float* __restrict__ mn,
                                              const float* __restrict__ g, const float* __restrict__ b,
                                              u16* __restrict__ zb) {
    __shared__ float red[4];
    int r = blockIdx.x, tid = threadIdx.x;
    float4 a = reinterpret_cast<const float4*>(y2 + (size_t)r * 1024)[tid];
    float4 c = reinterpret_cast<const float4*>(mn + (size_t)r * 1024)[tid];
    float4 v; v.x = a.x + c.x; v.y = a.y + c.y; v.z = a.z + c.z; v.w = a.w + c.w;
    float s  = v.x + v.y + v.z + v.w;
    float sq = v.x * v.x + v.y * v.y + v.z * v.z + v.w * v.w;
    s  = blk_sum(s, red);
    sq = blk_sum(sq, red);
    float mu = s * (1.0f / 1024.0f);
    float rs = rsqrtf(sq * (1.0f / 1024.0f) - mu * mu + LN_EPS);
    float4 gg = reinterpret_cast<const float4*>(g)[tid];
    float4 bb = reinterpret_cast<const float4*>(b)[tid];
    ushort4 o;
    o.x = f2bf((v.x - mu) * rs * gg.x + bb.x);
    o.y = f2bf((v.y - mu) * rs * gg.y + bb.y);
    o.z = f2bf((v.z - mu) * rs * gg.z + bb.z);
    o.w = f2bf((v.w - mu) * rs * gg.w + bb.w);
    reinterpret_cast<ushort4*>(zb + (size_t)r * 1024)[tid] = o;
}

__global__ __launch_bounds__(256) void ln_dot_k(const float* __restrict__ h, const float* __restrict__ g,
                                                const float* __restrict__ b, const float* __restrict__ kd,
                                                const float* __restrict__ kdb, float* __restrict__ out) {
    __shared__ float red[4];
    int r = blockIdx.x, tid = threadIdx.x;
    float4 v = reinterpret_cast<const float4*>(h + (size_t)r * 1024)[tid];
    float s  = v.x + v.y + v.z + v.w;
    float sq = v.x * v.x + v.y * v.y + v.z * v.z + v.w * v.w;
    s  = blk_sum(s, red);
    sq = blk_sum(sq, red);
    float mu = s * (1.0f / 1024.0f);
    float rs = rsqrtf(sq * (1.0f / 1024.0f) - mu * mu + LN_EPS);
    float4 gg = reinterpret_cast<const float4*>(g)[tid];
    float4 bb = reinterpret_cast<const float4*>(b)[tid];
    float4 kk = reinterpret_cast<const float4*>(kd)[tid];
    float part = ((v.x - mu) * rs * gg.x + bb.x) * kk.x
               + ((v.y - mu) * rs * gg.y + bb.y) * kk.y
               + ((v.z - mu) * rs * gg.z + bb.z) * kk.z
               + ((v.w - mu) * rs * gg.w + bb.w) * kk.w;
    part = blk_sum(part, red);
    if (tid == 0) out[r] = 1.0f / (1.0f + __expf(-(part + kdb[0])));
}

// ---------------- launch ----------------
extern "C" void kernel_launch(void* const* d_in, const int* in_sizes, int n_in,
                              void* d_out, int out_size, void* d_ws, size_t ws_size,
                              hipStream_t stream) {
    (void)in_sizes; (void)n_in; (void)out_size; (void)ws_size;
    const float* x    = (const float*)d_in[0];
    const float* Wq   = (const float*)d_in[2];
    const float* Wk   = (const float*)d_in[3];
    const float* Wv   = (const float*)d_in[4];
    const float* Wo   = (const float*)d_in[5];
    const float* fc1w = (const float*)d_in[6];
    const float* fc1b = (const float*)d_in[7];
    const float* kaw  = (const float*)d_in[8];
    const float* kab  = (const float*)d_in[9];
    const float* kdw  = (const float*)d_in[10];
    const float* kdb  = (const float*)d_in[11];
    const float* lyg  = (const float*)d_in[12];
    const float* lyb  = (const float*)d_in[13];
    const float* lkg  = (const float*)d_in[14];
    const float* lkb  = (const float*)d_in[15];

    float* out0 = (float*)d_out;
    float* aw   = out0 + 8192;

    char* base = (char*)d_ws;
    size_t off = 0;
    auto alloc = [&](size_t bytes) -> char* {
        char* p = base + off;
        off += (bytes + 255) & ~(size_t)255;
        return p;
    };
    const size_t NM = 8192ULL * 1024ULL;
    u16*   ST   = (u16*)alloc(8192ULL * 8192ULL * 2);   // 128MB aw^T bf16 (normalized)
    u16*   Eb   = (u16*)alloc(8192ULL * 8192ULL * 2);   // 128MB E=exp(S) bf16 (unnormalized)
    u16*   xb   = (u16*)alloc(NM * 2);
    u16*   QKVb = (u16*)alloc(8192ULL * 3072ULL * 2);   // 48MB: cols [Q*0.06 | K | V]
    u16*   Vt   = (u16*)alloc(NM * 2);
    u16*   d1   = (u16*)alloc(NM * 2);                  // later reused as zb
    u16*   d2   = (u16*)alloc(NM * 2);
    u16*   d3   = (u16*)alloc(NM * 2);
    u16*   yb   = (u16*)alloc(NM * 2);
    float* mn   = (float*)alloc(NM * 4);
    float* y01  = (float*)alloc(NM * 4 * 2);            // PV split-K slices
    float* y2   = (float*)alloc(NM * 4);
    float* hbuf = (float*)alloc(NM * 4);
    u16*   Wqkv = (u16*)alloc(3072ULL * 1024ULL * 2);   // rows [Wq|Wk|Wv]
    u16*   fwb  = (u16*)alloc(1048576ULL * 2);
    u16*   Wob  = (u16*)alloc(1048576ULL * 2);
    u16*   kwb  = (u16*)alloc(1048576ULL * 2);
    float* psum = (float*)alloc(8192ULL * 128ULL * 4);  // 4MB logits partial sums
    float* rowl = (float*)alloc(8192ULL * 4);
    u16*   zb   = d1;

    // 1) converts: x (+fused diffs) and weights (Wq pre-scaled 0.06)
    diff3x_k<<<8192, 256, 0, stream>>>(x, d1, d2, d3, xb);
    cvt6_k<<<3072, 256, 0, stream>>>(Wq, Wk, Wv, fc1w, Wo, kaw,
                                     Wqkv, Wqkv + 1048576, Wqkv + 2097152, fwb, Wob, kwb);

    // 2) mn branch: 3x BN=128 gemm8; tail rows
    gemm8_k<128, 1, 1><<<dim3(8, 32), 512, 0, stream>>>(
        d1, 1024, fwb, 1024, mn, nullptr, fc1b, 1024, 1024, 0, 1.0f);
    gemm8_k<128, 2, 1><<<dim3(8, 32), 512, 0, stream>>>(
        d2, 1024, fwb, 1024, mn, nullptr, fc1b, 1024, 1024, 0, 1.0f);
    gemm8_k<128, 2, 1><<<dim3(8, 32), 512, 0, stream>>>(
        d3, 1024, fwb, 1024, mn, nullptr, fc1b, 1024, 1024, 0, 1.0f);
    tail_k<<<16, 256, 0, stream>>>(x, mn);

    // 3) merged QKV projection: QKVb = xb @ [Wq*0.06;Wk;Wv]^T
    gemm8_k<128, 3, 1><<<dim3(24, 32), 512, 0, stream>>>(
        xb, 1024, Wqkv, 1024, nullptr, QKVb, nullptr, 3072, 1024, 0, 1.0f);
    transpose_bf16<<<dim3(16, 128), 256, 0, stream>>>(QKVb + 2048, Vt, 3072, 8192);

    // 4) single-pass softmax chain: E = exp(QK^T) bf16 with fused partial
    //    row-sums (psum, no atomics) -> tiny reduce -> fused normalize +
    //    dual-write (aw f32 + ST bf16^T). stats_k's 128MB pass eliminated.
    gemm8_k<256, 5, 4><<<dim3(32, 8), 512, 0, stream>>>(
        QKVb, 3072, QKVb + 1024, 3072, psum, Eb, nullptr, 8192, 1024, 0, 1.0f);
    reduce_k<<<32, 256, 0, stream>>>(psum, rowl);
    nt_k<<<dim3(128, 128), 256, 0, stream>>>(Eb, rowl, aw, ST);

    // 5) PV split-K z=2 (BN=256, K=4096 per slice): y01 slices; yb = bf16(y0+y1)
    gemm8_k<256, 0, 1><<<dim3(4, 32, 2), 512, 0, stream>>>(
        ST, 8192, Vt, 8192, y01, nullptr, nullptr, 1024, 4096, NM, 1.0f);
    cvt2_k<<<4096, 256, 0, stream>>>(y01, y01 + NM, yb);

    // 6) head: y2 = yb@Wo^T ; zb = LN(y2+mn) ; h = relu(zb@ka^T+b) ; out
    gemm8_k<128, 0, 1><<<dim3(8, 32), 512, 0, stream>>>(
        yb, 1024, Wob, 1024, y2, nullptr, nullptr, 1024, 1024, 0, 1.0f);
    ln_y_k<<<8192, 256, 0, stream>>>(y2, mn, lyg, lyb, zb);
    gemm8_k<128, 1, 1><<<dim3(8, 32), 512, 0, stream>>>(
        zb, 1024, kwb, 1024, hbuf, nullptr, kab, 1024, 1024, 0, 1.0f);
    ln_dot_k<<<8192, 256, 0, stream>>>(hbuf, lkg, lkb, kdw, kdb, out0);
}